// Round 10
// baseline (172.020 us; speedup 1.0000x reference)
//
#include <hip/hip_runtime.h>
#include <math.h>

#define NN 588
#define EE 9408
#define HD 64
#define NBLK 16            // workers (all on ONE XCD)
#define LAUNCHB 128        // launched blocks; 16 land on each of 8 XCDs
#define NTHR 1024
#define NWAVE (NTHR/64)    // 16
#define GXROWS (192/NBLK)  // 12
#define NEGS 0.01f
#define THRESHV 0.999f
#define DROW NN
#define EPADCAP 13536      // >= 9408 + 588*7

struct Ctrl {
  int xcnt[8*16];          // per-XCD arrival counters (64B apart)
  int winner;  int padw[15];
  unsigned flags[NBLK*16]; // per-worker flag, own 64B line
};

__device__ __forceinline__ float lrelu(float v){ return v >= 0.f ? v : NEGS*v; }
__device__ __forceinline__ float sigm(float v){ return 1.f/(1.f+expf(-v)); }
__device__ __forceinline__ float rdlane(float v, int l){
  return __int_as_float(__builtin_amdgcn_readlane(__float_as_int(v), l));
}
__device__ __forceinline__ float wredsum(float v){
  v += __shfl_down(v,32); v += __shfl_down(v,16); v += __shfl_down(v,8);
  v += __shfl_down(v,4);  v += __shfl_down(v,2);  v += __shfl_down(v,1);
  return v;  // valid on lane 0
}
__device__ __forceinline__ float aload(const float* p){
  return __hip_atomic_load(p, __ATOMIC_RELAXED, __HIP_MEMORY_SCOPE_AGENT);
}
__device__ __forceinline__ void sink4(float4 v){
  asm volatile("" :: "v"(v.x), "v"(v.y), "v"(v.z), "v"(v.w));
}
__device__ __forceinline__ void prefetch_region(const float* p0, int nfloats, int t, int T){
  const float4* p = (const float4*)p0;
  const int n = nfloats >> 2;
  for (int base = t; base < n; base += T*8) {
    float4 v[8];
    #pragma unroll
    for (int u = 0; u < 8; ++u) { int i = base + u*T; if (i >= n) i = n - 1; v[u] = p[i]; }
    #pragma unroll
    for (int u = 0; u < 8; ++u) sink4(v[u]);
  }
}

// Same-XCD light barrier: __syncthreads drains vmcnt (write-through L1 -> L2),
// then relaxed flag store + poll. No threadfence: L2 is shared, never wiped.
__device__ __forceinline__ void gbarL(Ctrl* c, unsigned& g, int wid) {
  __syncthreads();
  ++g;
  if (threadIdx.x < 64) {
    int lane = threadIdx.x;
    if (lane == 0)
      __hip_atomic_store(&c->flags[wid*16], g, __ATOMIC_RELAXED, __HIP_MEMORY_SCOPE_AGENT);
    long bail = 0;
    for (;;) {
      int ok = (lane >= NBLK) ? 1 :
               (__hip_atomic_load(&c->flags[lane*16], __ATOMIC_RELAXED, __HIP_MEMORY_SCOPE_AGENT) >= g);
      if (__all(ok)) break;
      __builtin_amdgcn_s_sleep(1);
      if (++bail > (1L<<22)) break;
    }
  }
  __syncthreads();
}

__global__ __launch_bounds__(NTHR)
void lastgcn_kernel(const float* __restrict__ feat, const int* __restrict__ src,
                    const int* __restrict__ dst,
                    const float* __restrict__ W1, const float* __restrict__ b1,
                    const float* __restrict__ W2, const float* __restrict__ b2,
                    const float* __restrict__ W3, const float* __restrict__ b3,
                    const float* __restrict__ W5, const float* __restrict__ b5,
                    const float* __restrict__ wi, const float* __restrict__ wh,
                    const float* __restrict__ bi, const float* __restrict__ bh,
                    const float* __restrict__ w_end, const float* __restrict__ b_end,
                    const int* __restrict__ capp,
                    float* __restrict__ out, Ctrl* ctrl,
                    float* __restrict__ x0g, float* __restrict__ x1g,
                    float* __restrict__ ypub, float* __restrict__ gxpub,
                    float* __restrict__ ghpub) {
  const int tid  = threadIdx.x;
  const int lane = tid & 63;
  const int w    = tid >> 6;

  __shared__ int sWid;

  // ---- worker election: first XCD to seat NBLK blocks wins ----
  if (tid == 0) {
    unsigned xcc;
    asm volatile("s_getreg_b32 %0, hwreg(HW_REG_XCC_ID)" : "=s"(xcc));
    xcc &= 7u;
    int r = atomicAdd(&ctrl->xcnt[xcc*16], 1);
    if (r == NBLK-1) atomicCAS(&ctrl->winner, 0, (int)xcc + 1);
    int win; long bail = 0;
    do {
      win = __hip_atomic_load(&ctrl->winner, __ATOMIC_RELAXED, __HIP_MEMORY_SCOPE_AGENT);
      __builtin_amdgcn_s_sleep(1);
    } while (win == 0 && ++bail < (1L<<24));
    sWid = (win == (int)xcc + 1 && r < NBLK) ? r : -1;
  }
  __syncthreads();
  const int wid = sWid;
  if (wid < 0) return;

  const int nbeg = (NN*wid)/NBLK;
  const int nend = (NN*(wid+1))/NBLK;
  const int cnt  = nend - nbeg;          // 36 or 37
  const int r0   = wid*GXROWS;

  __shared__ float  W2L[64*64];             // 16384 B
  __shared__ unsigned short eidxL[EPADCAP]; // 27072 B
  __shared__ int    offL[NN+1];
  __shared__ int    curL[NN];
  __shared__ float  yF[NN+1];
  __shared__ float  inpF[NN];
  __shared__ float  stateL[64];
  __shared__ float4 f4L[40];
  __shared__ int    wsumL[NWAVE];
  __shared__ float  sScal[3];
  __shared__ int    sStop;
  unsigned mygen = 0;

  // ---- CSR build: waves 0-7 count degrees; waves 8-15 prefetch wi rows ----
  for (int i = tid; i < NN; i += NTHR) curL[i] = 0;
  for (int i = tid; i < 1024; i += NTHR) ((float4*)W2L)[i] = ((const float4*)W2)[i];
  __syncthreads();
  if (w < 8) {
    for (int e = tid; e < EE; e += 512) atomicAdd(&curL[dst[e]], 1);
  } else {
    const int pt = tid - 512, PT = 512;
    prefetch_region(wi + r0*NN, GXROWS*NN, pt, PT);   // my 12 rows (28 KB)
    prefetch_region(wh + r0*64, GXROWS*64, pt, PT);
    prefetch_region(w_end, 64, pt, PT);
  }
  __syncthreads();

  // ---- padded exclusive scan (wave-level, 2 stages) ----
  {
    const int n0 = 2*tid, n1 = n0 + 1;
    int d0 = (n0 < NN) ? curL[n0] : 0;
    int d1 = (n1 < NN) ? curL[n1] : 0;
    int p0 = (d0 + 7) & ~7, p1 = (d1 + 7) & ~7;
    int my = p0 + p1;
    int inc = my;
    for (int o = 1; o < 64; o <<= 1) { int u = __shfl_up(inc, o); if (lane >= o) inc += u; }
    if (lane == 63) wsumL[w] = inc;
    __syncthreads();
    if (w == 0 && lane < NWAVE) {
      int s0 = wsumL[lane];
      int is = s0;
      for (int o = 1; o < NWAVE; o <<= 1) { int u = __shfl_up(is, o); if (lane >= o) is += u; }
      wsumL[lane] = is - s0;   // exclusive
    }
    __syncthreads();
    int base = wsumL[w] + inc - my;
    if (n0 < NN) { offL[n0] = base;      curL[n0] = base; }
    if (n1 < NN) { offL[n1] = base + p0; curL[n1] = base + p0; }
    if (tid == NTHR-1) offL[NN] = base + p0 + p1;
  }
  __syncthreads();
  for (int e = tid; e < EE; e += NTHR) {
    int p = atomicAdd(&curL[dst[e]], 1);
    eidxL[p] = (unsigned short)src[e];
  }
  __syncthreads();
  {
    const int n0 = 2*tid, n1 = n0 + 1;
    if (n0 < NN) for (int k = curL[n0]; k < offL[n0+1]; ++k) eidxL[k] = (unsigned short)DROW;
    if (n1 < NN) for (int k = curL[n1]; k < offL[n1+1]; ++k) eidxL[k] = (unsigned short)DROW;
  }
  __syncthreads();

  // ---- conv1 on my partition ----
  if (tid < cnt) {
    int n = nbeg + tid;
    int o = offL[n], o1 = offL[n+1];
    float fx=0.f, fy=0.f, fz=0.f, fw2=0.f;
    for (int k = o; k < o1; k += 8) {
      uint4 q = *(const uint4*)(eidxL + k);
      int id[8] = { (int)(q.x & 0xFFFF), (int)(q.x >> 16), (int)(q.y & 0xFFFF), (int)(q.y >> 16),
                    (int)(q.z & 0xFFFF), (int)(q.z >> 16), (int)(q.w & 0xFFFF), (int)(q.w >> 16) };
      float4 tv[8]; float m[8];
      #pragma unroll
      for (int u = 0; u < 8; ++u) {
        int valid = id[u] < NN;
        m[u] = valid ? 1.f : 0.f;
        tv[u] = *(const float4*)(feat + (valid ? id[u] : 0)*4);
      }
      #pragma unroll
      for (int u = 0; u < 8; ++u) { fx += m[u]*tv[u].x; fy += m[u]*tv[u].y; fz += m[u]*tv[u].z; fw2 += m[u]*tv[u].w; }
    }
    f4L[tid] = make_float4(fx, fy, fz, fw2);
  }
  __syncthreads();
  const float W3r = W3[lane];
  for (int i = w; i < cnt; i += NWAVE) {
    int n = nbeg + i; float4 f = f4L[i];
    float v = b1[lane] + f.x*W1[lane] + f.y*W1[64+lane] + f.z*W1[128+lane] + f.w*W1[192+lane];
    v = lrelu(v);
    x0g[n*HD + lane] = v;
    float yv = wredsum(v * W3r);
    if (lane == 0) ypub[n] = yv;
  }
  gbarL(ctrl, mygen, wid);               // B1: x0 + y0 in shared L2

  const float b3v = b3[0];

  // inp (ALL nodes, from L2-fresh ypub) then my 12 gx rows -> publish -> barrier
  auto inp_gx = [&]() {
    for (int i = tid; i <= NN; i += NTHR) yF[i] = aload(ypub + i);
    __syncthreads();
    for (int n = tid; n < NN; n += NTHR) {
      int o = offL[n], o1 = offL[n+1];
      float a = 0.f;
      for (int k = o; k < o1; k += 8) {
        uint4 q = *(const uint4*)(eidxL + k);
        a += yF[q.x & 0xFFFF] + yF[q.x >> 16] + yF[q.y & 0xFFFF] + yF[q.y >> 16];
        a += yF[q.z & 0xFFFF] + yF[q.z >> 16] + yF[q.w & 0xFFFF] + yF[q.w >> 16];
      }
      inpF[n] = lrelu(a + b3v);
    }
    __syncthreads();
    const float4* inp4 = (const float4*)inpF;   // 147 float4s
    for (int rr = w; rr < GXROWS; rr += NWAVE) {
      const float4* row4 = (const float4*)(wi + (r0 + rr)*NN);
      float p = 0.f;
      #pragma unroll
      for (int k = 0; k < 3; ++k) {
        int c = lane + (k << 6);
        if (c < 147) {
          float4 a = row4[c], b = inp4[c];
          p += a.x*b.x + a.y*b.y + a.z*b.z + a.w*b.w;
        }
      }
      p = wredsum(p);
      if (lane == 0) gxpub[r0 + rr] = p + bi[r0 + rr];
    }
    gbarL(ctrl, mygen, wid);             // B_gx
  };

  inp_gx();

  // ---- GRU init, replicated in every worker ----
  if (w == 0) {
    int j = lane;
    float gx0 = aload(gxpub + j), gx1 = aload(gxpub + 64 + j), gx2 = aload(gxpub + 128 + j);
    float r  = sigm(gx0 + bh[j]);
    float z  = sigm(gx1 + bh[64+j]);
    float n2 = tanhf(gx2 + r*bh[128+j]);
    float st = (1.f - z)*n2;             // h0 = 0
    stateL[j] = st;
    float t2 = wredsum(st * w_end[j]);
    if (j == 0) {
      float pr = sigm(t2 + b_end[0]);
      sScal[0] = pr; sScal[1] = pr; sScal[2] = 0.f;
      sStop = (pr >= THRESHV) ? 1 : 0;
    }
  }
  __syncthreads();
  // gh distributed: my 12 rows published (read by all after >=1 barrier)
  for (int rr = w; rr < GXROWS; rr += NWAVE) {
    int r = r0 + rr;
    float p = wredsum(wh[r*64 + lane] * stateL[lane]);
    if (lane == 0) ghpub[r] = p + bh[r];
  }
  __syncthreads();

  // ---- main loop ----
  const int cap = capp[0];
  float* xc = x0g;
  float* xn = x1g;
  const float b2r = b2[lane];
  for (int it = 0; it < cap; ++it) {
    if (sStop) break;                    // uniform (replicated GRU)

    // conv2: node pairs per wave
    for (int i = w; i < cnt; i += 2*NWAVE) {
      int i2 = i + NWAVE;
      bool has2 = (i2 < cnt);
      int nA = nbeg + i, nB = nbeg + (has2 ? i2 : i);
      int oA = offL[nA], lA = offL[nA+1] - oA;
      int oB = offL[nB], lB = offL[nB+1] - oB;
      float accA = 0.f, accB = 0.f;
      int pcm = lA > lB ? lA : lB;
      for (int k = 0; k < pcm; k += 8) {
        float ta[8], tb[8];
        if (k < lA) {
          uint4 q = *(const uint4*)(eidxL + oA + k);
          ta[0] = xc[(int)(q.x & 0xFFFF)*HD + lane]; ta[1] = xc[(int)(q.x >> 16)*HD + lane];
          ta[2] = xc[(int)(q.y & 0xFFFF)*HD + lane]; ta[3] = xc[(int)(q.y >> 16)*HD + lane];
          ta[4] = xc[(int)(q.z & 0xFFFF)*HD + lane]; ta[5] = xc[(int)(q.z >> 16)*HD + lane];
          ta[6] = xc[(int)(q.w & 0xFFFF)*HD + lane]; ta[7] = xc[(int)(q.w >> 16)*HD + lane];
        } else { for (int u = 0; u < 8; ++u) ta[u] = 0.f; }
        if (k < lB) {
          uint4 q = *(const uint4*)(eidxL + oB + k);
          tb[0] = xc[(int)(q.x & 0xFFFF)*HD + lane]; tb[1] = xc[(int)(q.x >> 16)*HD + lane];
          tb[2] = xc[(int)(q.y & 0xFFFF)*HD + lane]; tb[3] = xc[(int)(q.y >> 16)*HD + lane];
          tb[4] = xc[(int)(q.z & 0xFFFF)*HD + lane]; tb[5] = xc[(int)(q.z >> 16)*HD + lane];
          tb[6] = xc[(int)(q.w & 0xFFFF)*HD + lane]; tb[7] = xc[(int)(q.w >> 16)*HD + lane];
        } else { for (int u = 0; u < 8; ++u) tb[u] = 0.f; }
        #pragma unroll
        for (int u = 0; u < 8; ++u) { accA += ta[u]; accB += tb[u]; }
      }
      float a0=0.f,a1=0.f,a2=0.f,a3=0.f, c0=0.f,c1=0.f,c2=0.f,c3=0.f;
      #pragma unroll
      for (int l = 0; l < 64; l += 4) {
        float w0 = W2L[(l+0)*64 + lane];
        float w1v = W2L[(l+1)*64 + lane];
        float w2v = W2L[(l+2)*64 + lane];
        float w3v = W2L[(l+3)*64 + lane];
        a0 = fmaf(rdlane(accA,l+0), w0,  a0);  c0 = fmaf(rdlane(accB,l+0), w0,  c0);
        a1 = fmaf(rdlane(accA,l+1), w1v, a1);  c1 = fmaf(rdlane(accB,l+1), w1v, c1);
        a2 = fmaf(rdlane(accA,l+2), w2v, a2);  c2 = fmaf(rdlane(accB,l+2), w2v, c2);
        a3 = fmaf(rdlane(accA,l+3), w3v, a3);  c3 = fmaf(rdlane(accB,l+3), w3v, c3);
      }
      {
        float vA = lrelu(b2r + (a0+a1)+(a2+a3));
        xn[nA*HD + lane] = vA;
        float yv = wredsum(vA * W3r);
        if (lane == 0) ypub[nA] = yv;
      }
      if (has2) {
        float vB = lrelu(b2r + (c0+c1)+(c2+c3));
        xn[nB*HD + lane] = vB;
        float yv = wredsum(vB * W3r);
        if (lane == 0) ypub[nB] = yv;
      }
    }
    gbarL(ctrl, mygen, wid);             // B_a: xn + y in shared L2

    inp_gx();                            // inp + gx + B_gx

    if (w == 0) {                        // GRU tail, replicated
      int j = lane;
      float gx0 = aload(gxpub + j), gx1 = aload(gxpub + 64 + j), gx2 = aload(gxpub + 128 + j);
      float gh0 = aload(ghpub + j), gh1 = aload(ghpub + 64 + j), gh2 = aload(ghpub + 128 + j);
      float r  = sigm(gx0 + gh0);
      float z  = sigm(gx1 + gh1);
      float n2 = tanhf(gx2 + r*gh2);
      float st = (1.f - z)*n2 + z*stateL[j];   // frozen state
      float t2 = wredsum(st * w_end[j]);
      if (j == 0) {
        float pr = sigm(t2 + b_end[0]);
        float s = sScal[0] + pr;
        sScal[0] = s; sScal[1] = pr; sScal[2] += 1.f;
        sStop = (s >= THRESHV) ? 1 : 0;
      }
    }
    __syncthreads();
    { float* t = xc; xc = xn; xn = t; }
  }

  // ---- final conv on my partition ----
  for (int i = w; i < cnt; i += NWAVE) {
    int n = nbeg + i;
    int o = offL[n], o1 = offL[n+1];
    float acc = 0.f;
    for (int k = o; k < o1; k += 8) {
      uint4 q = *(const uint4*)(eidxL + k);
      float t[8];
      t[0] = xc[(int)(q.x & 0xFFFF)*HD + lane]; t[1] = xc[(int)(q.x >> 16)*HD + lane];
      t[2] = xc[(int)(q.y & 0xFFFF)*HD + lane]; t[3] = xc[(int)(q.y >> 16)*HD + lane];
      t[4] = xc[(int)(q.z & 0xFFFF)*HD + lane]; t[5] = xc[(int)(q.z >> 16)*HD + lane];
      t[6] = xc[(int)(q.w & 0xFFFF)*HD + lane]; t[7] = xc[(int)(q.w >> 16)*HD + lane];
      #pragma unroll
      for (int u = 0; u < 8; ++u) acc += t[u];
    }
    float p0 = wredsum(acc * W5[lane*3 + 0]);
    float p1 = wredsum(acc * W5[lane*3 + 1]);
    float p2 = wredsum(acc * W5[lane*3 + 2]);
    if (lane == 0) {
      out[n*3 + 0] = p0 + b5[0];
      out[n*3 + 1] = p1 + b5[1];
      out[n*3 + 2] = p2 + b5[2];
    }
  }
  if (wid == 0 && tid == 0) {
    out[NN*3]     = sScal[2];  // counter (as float)
    out[NN*3 + 1] = sScal[1];  // fprob
  }
}

extern "C" void kernel_launch(void* const* d_in, const int* in_sizes, int n_in,
                              void* d_out, int out_size, void* d_ws, size_t ws_size,
                              hipStream_t stream) {
  const float* feat  = (const float*)d_in[0];
  const int*   src   = (const int*)d_in[1];
  const int*   dst   = (const int*)d_in[2];
  const float* W1    = (const float*)d_in[3];
  const float* b1    = (const float*)d_in[4];
  const float* W2    = (const float*)d_in[5];
  const float* b2    = (const float*)d_in[6];
  const float* W3    = (const float*)d_in[7];
  const float* b3    = (const float*)d_in[8];
  const float* W5    = (const float*)d_in[9];
  const float* b5    = (const float*)d_in[10];
  const float* wi    = (const float*)d_in[11];
  const float* wh    = (const float*)d_in[12];
  const float* bi    = (const float*)d_in[13];
  const float* bh    = (const float*)d_in[14];
  const float* w_end = (const float*)d_in[15];
  const float* b_end = (const float*)d_in[16];
  const int*   capp  = (const int*)d_in[17];

  float* out = (float*)d_out;
  char* wsb = (char*)d_ws;
  Ctrl*  ctrl   = (Ctrl*)wsb;                       // 4096 B reserved
  float* x0g    = (float*)(wsb + 4096);
  float* x1g    = x0g + (size_t)(NN+1)*HD;
  float* ypub   = x1g + (size_t)(NN+1)*HD;
  float* gxpub  = ypub + (NN+1);
  float* ghpub  = gxpub + 192;

  // Zero control words + dummy rows on-stream (graph-capturable).
  hipMemsetAsync(ctrl, 0, 4096, stream);
  hipMemsetAsync(x0g + (size_t)DROW*HD, 0, HD*sizeof(float), stream);
  hipMemsetAsync(x1g + (size_t)DROW*HD, 0, HD*sizeof(float), stream);
  hipMemsetAsync(ypub + NN, 0, sizeof(float), stream);

  lastgcn_kernel<<<dim3(LAUNCHB), dim3(NTHR), 0, stream>>>(
      feat, src, dst, W1, b1, W2, b2, W3, b3, W5, b5,
      wi, wh, bi, bh, w_end, b_end, capp, out,
      ctrl, x0g, x1g, ypub, gxpub, ghpub);
}